// Round 1
// baseline (501.160 us; speedup 1.0000x reference)
//
#include <hip/hip_runtime.h>
#include <hip/hip_cooperative_groups.h>

namespace cg = cooperative_groups;

#define N_NODES 100000
#define N_EDGES 3200000
#define NB2 512    // buckets == tiles == blocks; 2 blocks/CU on 256 CUs
#define BKN2 196   // nodes per bucket (512*196 = 100352 >= 100000)
#define RSZ2 7424  // per-bucket record window (mean 6272, +14.5 sigma)
#define TILE 6250  // 512*6250 == 3.2M exactly
#define MAXIT 13   // ceil(TILE/512)
#define MAXB2 15   // ceil(RSZ2/512)

// ---------------------------------------------------------------------------
// One cooperative kernel, 3 phases, 2 grid syncs:
//   A: proj1 (block b -> nodes [196b,196b+196)) + tile counting-scatter
//   B: per-bucket LDS counting sort + layer-1 agg (src list STAYS in LDS)
//   C: layer-2 agg from LDS src list + global p2 gather -> out
// Workspace: gcur NB2*16 | node_off/cnt (fallback only) | recs NB2*RSZ2 |
//            p1h 16N bf16 | q1b 16N f32 | p2/r2/deg N f32
// ---------------------------------------------------------------------------

union SM {
  struct { float sWl[512]; float sWr[512]; float sb[16]; } proj;
  struct {
    int hist[1024];           // counts -> exclusive scan (zero-padded)
    int delta[NB2];           // absolute_base - bstart per bucket
    int seg[512];
    int stage[TILE];
    unsigned short bid[TILE + 6];
  } sc;                       // 45.7 KB  (union max)
  struct {
    int hist[BKN2 + 4];
    int nstart[BKN2 + 4];
    float sWl2[16], sWr2[16];
    float sdeg[BKN2];
    float sr2[BKN2];
    int ssort[RSZ2];
  } so;                       // 33.0 KB
};

__device__ __forceinline__ float bf2f_lo(unsigned int w) {
  return __uint_as_float(w << 16);
}
__device__ __forceinline__ float bf2f_hi(unsigned int w) {
  return __uint_as_float(w & 0xFFFF0000u);
}
__device__ __forceinline__ unsigned short f2bf(float f) {
  unsigned int b = __float_as_uint(f);
  return (unsigned short)((b + 0x7FFFu + ((b >> 16) & 1u)) >> 16);
}

// ---------------- phase A: proj + tile scatter ----------------
__device__ __forceinline__ void phaseA(
    const float* __restrict__ x, const int* __restrict__ ei,
    const float* __restrict__ Wl1, const float* __restrict__ Wr1,
    const float* __restrict__ b1, unsigned short* __restrict__ p1h,
    float* __restrict__ q1b, int* __restrict__ gcur, int* __restrict__ recs,
    SM& sm) {
  const int t = threadIdx.x;
  const int kb = blockIdx.x;

  // --- proj for this block's 196 nodes (waves 0-3 active) ---
  sm.proj.sWl[t] = Wl1[t];
  sm.proj.sWr[t] = Wr1[t];
  if (t < 16) sm.proj.sb[t] = b1[t];
  __syncthreads();
  if (t < BKN2) {
    const int n = kb * BKN2 + t;
    if (n < N_NODES) {
      float xr[32];
      const float4* xp = (const float4*)(x + (size_t)n * 32);
#pragma unroll
      for (int j = 0; j < 8; ++j) {
        float4 v = xp[j];
        xr[4 * j + 0] = v.x;
        xr[4 * j + 1] = v.y;
        xr[4 * j + 2] = v.z;
        xr[4 * j + 3] = v.w;
      }
      float pv[16], qv[16];
#pragma unroll
      for (int hh = 0; hh < 16; ++hh) {
        float a = 0.f, b = 0.f;
#pragma unroll
        for (int i = 0; i < 32; ++i) {
          a = fmaf(xr[i], sm.proj.sWl[hh * 32 + i], a);
          b = fmaf(xr[i], sm.proj.sWr[hh * 32 + i], b);
        }
        pv[hh] = a;
        qv[hh] = b + sm.proj.sb[hh];
      }
      unsigned int w[8];
#pragma unroll
      for (int j = 0; j < 8; ++j)
        w[j] = (unsigned int)f2bf(pv[2 * j]) |
               ((unsigned int)f2bf(pv[2 * j + 1]) << 16);
      uint4* pp = (uint4*)(p1h + (size_t)n * 16);
      pp[0] = make_uint4(w[0], w[1], w[2], w[3]);
      pp[1] = make_uint4(w[4], w[5], w[6], w[7]);
      float4* qp = (float4*)(q1b + (size_t)n * 16);
#pragma unroll
      for (int j = 0; j < 4; ++j)
        qp[j] =
            make_float4(qv[4 * j], qv[4 * j + 1], qv[4 * j + 2], qv[4 * j + 3]);
    }
  }
  __syncthreads();

  // --- counting-sort scatter of this block's tile ---
  for (int i = t; i < 1024; i += 512) sm.sc.hist[i] = 0;
  __syncthreads();

  const int tb = kb * TILE;
  int rec[MAXIT], aux[MAXIT];  // aux = (bucket<<16) | rank
#pragma unroll
  for (int i = 0; i < MAXIT; ++i) {
    const int pos = t + i * 512;
    if (pos < TILE) {
      const int e = tb + pos;
      const int s = ei[e];
      const int d = ei[N_EDGES + e];
      const int k = (int)((unsigned)d / (unsigned)BKN2);
      const int rank = atomicAdd(&sm.sc.hist[k], 1);
      rec[i] = ((d - k * BKN2) << 17) | s;
      aux[i] = (k << 16) | rank;
    } else {
      aux[i] = -1;
    }
  }
  __syncthreads();

  // exclusive scan of hist[1024] with 512 threads
  const int s0 = sm.sc.hist[2 * t], s1 = sm.sc.hist[2 * t + 1];
  const int my = s0 + s1;
  sm.sc.seg[t] = my;
  __syncthreads();
#pragma unroll
  for (int o = 1; o < 512; o <<= 1) {
    const int a = (t >= o) ? sm.sc.seg[t - o] : 0;
    __syncthreads();
    sm.sc.seg[t] += a;
    __syncthreads();
  }
  const int ex = sm.sc.seg[t] - my;
  sm.sc.hist[2 * t] = ex;
  sm.sc.hist[2 * t + 1] = ex + s0;
  {
    const int b = 2 * t;
    if (b < NB2 && s0)
      sm.sc.delta[b] = b * RSZ2 + atomicAdd(&gcur[b * 16], s0) - ex;
    if (b + 1 < NB2 && s1)
      sm.sc.delta[b + 1] =
          (b + 1) * RSZ2 + atomicAdd(&gcur[(b + 1) * 16], s1) - (ex + s0);
  }
  __syncthreads();

  // atomic-free placement + per-pos bucket id
#pragma unroll
  for (int i = 0; i < MAXIT; ++i) {
    if (aux[i] >= 0)
      sm.sc.stage[sm.sc.hist[aux[i] >> 16] + (aux[i] & 0xFFFF)] = rec[i];
  }
  {  // NB2 == blockDim: exactly one bucket per thread
    const int st = sm.sc.hist[t];
    const int en = sm.sc.hist[t + 1];
    for (int p = st; p < en; ++p) sm.sc.bid[p] = (unsigned short)t;
  }
  __syncthreads();

  // write-out in position order; per-bucket clamp prevents cross corruption
  for (int pos = t; pos < TILE; pos += 512) {
    const int bb = sm.sc.bid[pos];
    const int idx = sm.sc.delta[bb] + pos;
    if (idx < (bb + 1) * RSZ2) recs[idx] = sm.sc.stage[pos];
  }
}

// ---------------- phase B: bucket sort + layer-1 agg ----------------
template <bool FUSED>
__device__ __forceinline__ void phaseB(
    const int* __restrict__ gcur, int* __restrict__ recs,
    const unsigned short* __restrict__ p1h, const float* __restrict__ q1b,
    const float* __restrict__ Wl2, const float* __restrict__ Wr2,
    float* __restrict__ p2, float* __restrict__ r2g, float* __restrict__ degg,
    int* __restrict__ node_off, int* __restrict__ node_cnt, SM& sm) {
  const int t = threadIdx.x;
  const int kb = blockIdx.x;
  const int b0 = kb * RSZ2;
  const int cnt = min(gcur[kb * 16], RSZ2);
  const int gend = b0 + cnt;
  if (t < BKN2 + 4) sm.so.hist[t] = 0;
  if (t < 16) {
    sm.so.sWl2[t] = Wl2[t];
    sm.so.sWr2[t] = Wr2[t];
  }
  __syncthreads();

  int rc[MAXB2], ax[MAXB2];  // ax = (local<<13) | rank
#pragma unroll
  for (int i = 0; i < MAXB2; ++i) {
    const int r = b0 + t + i * 512;
    if (r < gend) {
      const int rv = recs[r];
      const int local = rv >> 17;
      const int rank = atomicAdd(&sm.so.hist[local], 1);
      rc[i] = rv & 0x1FFFF;
      ax[i] = (local << 13) | rank;
    } else {
      ax[i] = -1;
    }
  }
  __syncthreads();

  // exclusive scan of hist[0..BKN2] -> nstart
  {
    int v = (t <= BKN2) ? sm.so.hist[t] : 0;
    if (t <= BKN2) sm.so.nstart[t] = v;
    __syncthreads();
#pragma unroll
    for (int o = 1; o < BKN2 + 1; o <<= 1) {
      const int a = (t <= BKN2 && t >= o) ? sm.so.nstart[t - o] : 0;
      __syncthreads();
      if (t <= BKN2) sm.so.nstart[t] += a;
      __syncthreads();
    }
    if (t <= BKN2) sm.so.nstart[t] -= v;
  }
  __syncthreads();

#pragma unroll
  for (int i = 0; i < MAXB2; ++i) {
    if (ax[i] >= 0)
      sm.so.ssort[sm.so.nstart[ax[i] >> 13] + (ax[i] & 0x1FFF)] = rc[i];
  }
  __syncthreads();

  if (!FUSED) {  // fallback path only: persist CSR to global
    for (int j2 = t; j2 < cnt; j2 += 512) recs[b0 + j2] = sm.so.ssort[j2];
    if (t < BKN2) {
      const int n2 = kb * BKN2 + t;
      if (n2 < N_NODES) {
        node_off[n2] = b0 + sm.so.nstart[t];
        node_cnt[n2] = sm.so.hist[t];
      }
    }
  }

  // aggregation: 4 lanes/node; quad = (edge-parity<<1)|channel-half
  const int quad = t & 3;
  const int half = quad & 1;
  const int epar = quad >> 1;
  const unsigned short* pb = p1h + half * 8;
#pragma unroll
  for (int p = 0; p < 2; ++p) {
    const int local = p * 128 + (t >> 2);
    if (local >= BKN2) continue;
    const int n = kb * BKN2 + local;
    if (n >= N_NODES) continue;
    const int st = sm.so.nstart[local];
    const int k = sm.so.hist[local];

    float acc[8];
#pragma unroll
    for (int i = 0; i < 8; ++i) acc[i] = 0.f;
    int j = epar;
    for (; j + 6 < k; j += 8) {
      const int s0 = sm.so.ssort[st + j], s1 = sm.so.ssort[st + j + 2],
                s2 = sm.so.ssort[st + j + 4], s3 = sm.so.ssort[st + j + 6];
      const uint4 w0 = *(const uint4*)(pb + (size_t)s0 * 16);
      const uint4 w1 = *(const uint4*)(pb + (size_t)s1 * 16);
      const uint4 w2 = *(const uint4*)(pb + (size_t)s2 * 16);
      const uint4 w3 = *(const uint4*)(pb + (size_t)s3 * 16);
      acc[0] +=
          (bf2f_lo(w0.x) + bf2f_lo(w1.x)) + (bf2f_lo(w2.x) + bf2f_lo(w3.x));
      acc[1] +=
          (bf2f_hi(w0.x) + bf2f_hi(w1.x)) + (bf2f_hi(w2.x) + bf2f_hi(w3.x));
      acc[2] +=
          (bf2f_lo(w0.y) + bf2f_lo(w1.y)) + (bf2f_lo(w2.y) + bf2f_lo(w3.y));
      acc[3] +=
          (bf2f_hi(w0.y) + bf2f_hi(w1.y)) + (bf2f_hi(w2.y) + bf2f_hi(w3.y));
      acc[4] +=
          (bf2f_lo(w0.z) + bf2f_lo(w1.z)) + (bf2f_lo(w2.z) + bf2f_lo(w3.z));
      acc[5] +=
          (bf2f_hi(w0.z) + bf2f_hi(w1.z)) + (bf2f_hi(w2.z) + bf2f_hi(w3.z));
      acc[6] +=
          (bf2f_lo(w0.w) + bf2f_lo(w1.w)) + (bf2f_lo(w2.w) + bf2f_lo(w3.w));
      acc[7] +=
          (bf2f_hi(w0.w) + bf2f_hi(w1.w)) + (bf2f_hi(w2.w) + bf2f_hi(w3.w));
    }
    for (; j < k; j += 2) {
      const uint4 w = *(const uint4*)(pb + (size_t)sm.so.ssort[st + j] * 16);
      acc[0] += bf2f_lo(w.x);
      acc[1] += bf2f_hi(w.x);
      acc[2] += bf2f_lo(w.y);
      acc[3] += bf2f_hi(w.y);
      acc[4] += bf2f_lo(w.z);
      acc[5] += bf2f_hi(w.z);
      acc[6] += bf2f_lo(w.w);
      acc[7] += bf2f_hi(w.w);
    }
#pragma unroll
    for (int i = 0; i < 8; ++i) acc[i] += __shfl_xor(acc[i], 2);

    const float di = 1.f / fmaxf((float)k, 1.f);
    const float4* qp = (const float4*)(q1b + (size_t)n * 16 + half * 8);
    const float4 qa = qp[0], qb = qp[1];
    float h[8];
    h[0] = fmaxf(fmaf(acc[0], di, qa.x), 0.f);
    h[1] = fmaxf(fmaf(acc[1], di, qa.y), 0.f);
    h[2] = fmaxf(fmaf(acc[2], di, qa.z), 0.f);
    h[3] = fmaxf(fmaf(acc[3], di, qa.w), 0.f);
    h[4] = fmaxf(fmaf(acc[4], di, qb.x), 0.f);
    h[5] = fmaxf(fmaf(acc[5], di, qb.y), 0.f);
    h[6] = fmaxf(fmaf(acc[6], di, qb.z), 0.f);
    h[7] = fmaxf(fmaf(acc[7], di, qb.w), 0.f);
    float pa = 0.f, pbv = 0.f;
#pragma unroll
    for (int i = 0; i < 8; ++i) {
      pa = fmaf(h[i], sm.so.sWl2[half * 8 + i], pa);
      pbv = fmaf(h[i], sm.so.sWr2[half * 8 + i], pbv);
    }
    pa += __shfl_xor(pa, 1);
    pbv += __shfl_xor(pbv, 1);
    if (quad == 0) {
      p2[n] = pa;
      if (FUSED) {
        sm.so.sr2[local] = pbv;
        sm.so.sdeg[local] = di;
      } else {
        r2g[n] = pbv;
        degg[n] = di;
      }
    }
  }
}

// ---------------- phase C: layer-2 agg + epilogue ----------------
template <bool FUSED>
__device__ __forceinline__ void phaseC(
    const int* __restrict__ node_off, const int* __restrict__ node_cnt,
    const int* __restrict__ recs, const float* __restrict__ p2,
    const float* __restrict__ r2g, const float* __restrict__ degg,
    const float* __restrict__ b2, float* __restrict__ out, SM& sm) {
  const int t = threadIdx.x;
  const int kb = blockIdx.x;
  const int quad = t & 3;
  const float bias = b2[0];
#pragma unroll
  for (int p = 0; p < 2; ++p) {
    const int local = p * 128 + (t >> 2);
    if (local >= BKN2) continue;
    const int n = kb * BKN2 + local;
    if (n >= N_NODES) continue;
    int st, k;
    if (FUSED) {
      st = sm.so.nstart[local];
      k = sm.so.hist[local];
    } else {
      st = node_off[n];
      k = node_cnt[n];
    }

    float u = 0.f;
    int j = quad;
    if (FUSED) {
      for (; j + 12 < k; j += 16) {
        const int sA = sm.so.ssort[st + j], sB = sm.so.ssort[st + j + 4],
                  sC = sm.so.ssort[st + j + 8], sD = sm.so.ssort[st + j + 12];
        u += (p2[sA] + p2[sB]) + (p2[sC] + p2[sD]);
      }
      for (; j < k; j += 4) u += p2[sm.so.ssort[st + j]];
    } else {
      const int* sl = recs + st;
      for (; j + 12 < k; j += 16) {
        const int sA = sl[j], sB = sl[j + 4], sC = sl[j + 8], sD = sl[j + 12];
        u += (p2[sA] + p2[sB]) + (p2[sC] + p2[sD]);
      }
      for (; j < k; j += 4) u += p2[sl[j]];
    }
    u += __shfl_xor(u, 1);
    u += __shfl_xor(u, 2);
    if (quad == 0) {
      const float di = FUSED ? sm.so.sdeg[local] : degg[n];
      const float rv = FUSED ? sm.so.sr2[local] : r2g[n];
      out[n] = fmaf(u, di, rv + bias);
    }
  }
}

// ---------------- fused cooperative kernel ----------------
__global__ __launch_bounds__(512, 4) void k_fused(
    const float* x, const int* ei, const float* Wl1, const float* Wr1,
    const float* b1, const float* Wl2, const float* Wr2, const float* b2,
    unsigned short* p1h, float* q1b, int* gcur, int* recs, float* p2,
    float* out) {
  __shared__ SM sm;
  cg::grid_group g = cg::this_grid();
  phaseA(x, ei, Wl1, Wr1, b1, p1h, q1b, gcur, recs, sm);
  __threadfence();
  g.sync();
  phaseB<true>(gcur, recs, p1h, q1b, Wl2, Wr2, p2, nullptr, nullptr, nullptr,
               nullptr, sm);
  __threadfence();
  g.sync();
  phaseC<true>(nullptr, nullptr, recs, p2, nullptr, nullptr, b2, out, sm);
}

// ---------------- fallback (non-cooperative) path ----------------
__global__ __launch_bounds__(512, 4) void k_pA(const float* x, const int* ei,
                                               const float* Wl1,
                                               const float* Wr1,
                                               const float* b1,
                                               unsigned short* p1h, float* q1b,
                                               int* gcur, int* recs) {
  __shared__ SM sm;
  phaseA(x, ei, Wl1, Wr1, b1, p1h, q1b, gcur, recs, sm);
}
__global__ __launch_bounds__(512, 4) void k_pB(
    const int* gcur, int* recs, const unsigned short* p1h, const float* q1b,
    const float* Wl2, const float* Wr2, float* p2, float* r2g, float* degg,
    int* node_off, int* node_cnt) {
  __shared__ SM sm;
  phaseB<false>(gcur, recs, p1h, q1b, Wl2, Wr2, p2, r2g, degg, node_off,
                node_cnt, sm);
}
__global__ __launch_bounds__(512, 4) void k_pC(
    const int* node_off, const int* node_cnt, const int* recs, const float* p2,
    const float* r2g, const float* degg, const float* b2, float* out) {
  __shared__ SM sm;
  phaseC<false>(node_off, node_cnt, recs, p2, r2g, degg, b2, out, sm);
}

extern "C" void kernel_launch(void* const* d_in, const int* in_sizes, int n_in,
                              void* d_out, int out_size, void* d_ws,
                              size_t ws_size, hipStream_t stream) {
  const float* x = (const float*)d_in[0];
  const int* ei = (const int*)d_in[1];
  const float* Wl1 = (const float*)d_in[2];
  const float* Wr1 = (const float*)d_in[3];
  const float* b1 = (const float*)d_in[4];
  const float* Wl2 = (const float*)d_in[5];
  const float* Wr2 = (const float*)d_in[6];
  const float* b2 = (const float*)d_in[7];
  float* out = (float*)d_out;

  const size_t N = N_NODES;
  int* wi = (int*)d_ws;
  int* gcur = wi;                        // NB2*16 = 8192 ints
  int* node_off = wi + NB2 * 16;         // 100352 (fallback only)
  int* node_cnt = node_off + 100352;     // 100352 (fallback only)
  int* recs = node_cnt + 100352;         // NB2*RSZ2 = 3,801,088 ints
  unsigned short* p1h = (unsigned short*)(recs + (size_t)NB2 * RSZ2);
  float* q1b = (float*)(p1h + 16 * N);   // 16N floats
  float* p2 = q1b + 16 * N;
  float* r2 = p2 + N;
  float* degg = r2 + N;

  hipMemsetAsync(gcur, 0, NB2 * 16 * sizeof(int), stream);

  void* ka[] = {(void*)&x,   (void*)&ei,  (void*)&Wl1, (void*)&Wr1,
                (void*)&b1,  (void*)&Wl2, (void*)&Wr2, (void*)&b2,
                (void*)&p1h, (void*)&q1b, (void*)&gcur, (void*)&recs,
                (void*)&p2,  (void*)&out};
  hipError_t err = hipLaunchCooperativeKernel(
      reinterpret_cast<void*>(k_fused), dim3(NB2), dim3(512), ka, 0, stream);
  if (err != hipSuccess) {
    (void)hipGetLastError();  // clear sticky error, use fallback path
    k_pA<<<NB2, 512, 0, stream>>>(x, ei, Wl1, Wr1, b1, p1h, q1b, gcur, recs);
    k_pB<<<NB2, 512, 0, stream>>>(gcur, recs, p1h, q1b, Wl2, Wr2, p2, r2, degg,
                                  node_off, node_cnt);
    k_pC<<<NB2, 512, 0, stream>>>(node_off, node_cnt, recs, p2, r2, degg, b2,
                                  out);
  }
}

// Round 2
// 172.029 us; speedup vs baseline: 2.9132x; 2.9132x over previous
//
#include <hip/hip_runtime.h>

#define N_NODES 100000
#define N_EDGES 3200000
#define NB 1024                        // buckets: exactly 4 blocks/CU
#define BKN 98                         // nodes per bucket (1024*98=100352)
#define RSZ 3968                       // record window (mean 3136, +14.9 sigma)
#define TILE 6250
#define NTILES 512                     // 512*6250 == 3.2M exactly; 2 blocks/CU
#define MAXIT 13                       // ceil(TILE/512)
#define MAXB 8                         // ceil(RSZ/512)

// ---------------------------------------------------------------------------
// 4-kernel structure (round-0 style; fusion regressed 3x due to L2
// invalidation at grid.sync + occupancy loss):
//   k_proj1    : x @ Wl1/Wr1 -> p1h (bf16), q1b (f32); zero gcur
//   k_bscatter : tile counting-sort scatter of edges into 1024 dst-buckets
//   k_sortagg1 : per-bucket LDS counting sort + layer-1 agg + layer-2 proj
//                (sorted list stays in LDS; NO write-back)
//   k_agg2out  : layer-2 agg over pass-A-ordered recs via LDS atomicAdd
// Workspace: gcur NB*16 | recs NB*RSZ | p1h 16N bf16 | q1b 16N f32 |
//            p2/r2/deg_inv N f32
// ---------------------------------------------------------------------------

__device__ __forceinline__ float bf2f_lo(unsigned int w) {
  return __uint_as_float(w << 16);
}
__device__ __forceinline__ float bf2f_hi(unsigned int w) {
  return __uint_as_float(w & 0xFFFF0000u);
}
__device__ __forceinline__ unsigned short f2bf(float f) {
  unsigned int b = __float_as_uint(f);
  return (unsigned short)((b + 0x7FFFu + ((b >> 16) & 1u)) >> 16);
}

// proj1 + gcur zero-init. 256-thread blocks x 391 -> all 256 CUs covered.
__global__ __launch_bounds__(256) void k_proj1(
    const float* __restrict__ x, const float* __restrict__ Wl1,
    const float* __restrict__ Wr1, const float* __restrict__ b1,
    unsigned short* __restrict__ p1h, float* __restrict__ q1b,
    int* __restrict__ gcur) {
  __shared__ float sWl[512];
  __shared__ float sWr[512];
  __shared__ float sb[16];
  const int t = threadIdx.x;
  if (t < 64) {
    const int gi = blockIdx.x * 64 + t;
    if (gi < NB * 16) gcur[gi] = 0;
  }
  for (int i = t; i < 512; i += 256) {
    sWl[i] = Wl1[i];
    sWr[i] = Wr1[i];
  }
  if (t < 16) sb[t] = b1[t];
  __syncthreads();

  const int n = blockIdx.x * 256 + t;
  if (n >= N_NODES) return;

  float xr[32];
  const float4* xp = (const float4*)(x + (size_t)n * 32);
#pragma unroll
  for (int j = 0; j < 8; ++j) {
    float4 v = xp[j];
    xr[4 * j + 0] = v.x;
    xr[4 * j + 1] = v.y;
    xr[4 * j + 2] = v.z;
    xr[4 * j + 3] = v.w;
  }
  float pv[16], qv[16];
#pragma unroll
  for (int hh = 0; hh < 16; ++hh) {
    float a = 0.f, b = 0.f;
#pragma unroll
    for (int i = 0; i < 32; ++i) {
      a = fmaf(xr[i], sWl[hh * 32 + i], a);
      b = fmaf(xr[i], sWr[hh * 32 + i], b);
    }
    pv[hh] = a;
    qv[hh] = b + sb[hh];
  }
  unsigned int w[8];
#pragma unroll
  for (int j = 0; j < 8; ++j)
    w[j] = (unsigned int)f2bf(pv[2 * j]) |
           ((unsigned int)f2bf(pv[2 * j + 1]) << 16);
  uint4* pp = (uint4*)(p1h + (size_t)n * 16);
  pp[0] = make_uint4(w[0], w[1], w[2], w[3]);
  pp[1] = make_uint4(w[4], w[5], w[6], w[7]);
  float4* qp = (float4*)(q1b + (size_t)n * 16);
#pragma unroll
  for (int j = 0; j < 4; ++j)
    qp[j] = make_float4(qv[4 * j], qv[4 * j + 1], qv[4 * j + 2], qv[4 * j + 3]);
}

// Standalone tile counting-sort scatter: rank trick (1 LDS atomic/record) +
// bid/delta write-out. 512x512 = 2/CU. NB=1024 -> hist is exact-fit.
__global__ __launch_bounds__(512) void k_bscatter(const int* __restrict__ ei,
                                                  int* __restrict__ gcur,
                                                  int* __restrict__ recs) {
  __shared__ int hist[1024];   // counts -> exclusive scan (bstart)
  __shared__ int delta[NB];    // absolute_base - bstart per bucket
  __shared__ int seg[512];
  __shared__ int stage[TILE];
  __shared__ unsigned short bid[TILE + 6];  // per-pos bucket id
  const int t = threadIdx.x;
  for (int i = t; i < 1024; i += 512) hist[i] = 0;
  __syncthreads();

  const int tb = blockIdx.x * TILE;
  int rec[MAXIT], aux[MAXIT];  // aux = (bucket<<16) | rank
#pragma unroll
  for (int i = 0; i < MAXIT; ++i) {
    const int pos = t + i * 512;
    if (pos < TILE) {
      const int e = tb + pos;
      const int s = ei[e];
      const int d = ei[N_EDGES + e];
      const int k = (int)((unsigned)d / (unsigned)BKN);
      const int rank = atomicAdd(&hist[k], 1);
      rec[i] = ((d - k * BKN) << 17) | s;
      aux[i] = (k << 16) | rank;
    } else {
      aux[i] = -1;
    }
  }
  __syncthreads();

  // exclusive scan of hist[1024] with 512 threads (2 elems/thread)
  const int s0 = hist[2 * t], s1 = hist[2 * t + 1];
  const int my = s0 + s1;
  seg[t] = my;
  __syncthreads();
#pragma unroll
  for (int o = 1; o < 512; o <<= 1) {
    const int a = (t >= o) ? seg[t - o] : 0;
    __syncthreads();
    seg[t] += a;
    __syncthreads();
  }
  const int ex = seg[t] - my;
  hist[2 * t] = ex;
  hist[2 * t + 1] = ex + s0;
  // global reservation; delta[k] = absolute_base - bstart[k]
  {
    const int b = 2 * t;
    if (s0) delta[b] = b * RSZ + atomicAdd(&gcur[b * 16], s0) - ex;
    if (s1)
      delta[b + 1] =
          (b + 1) * RSZ + atomicAdd(&gcur[(b + 1) * 16], s1) - (ex + s0);
  }
  __syncthreads();

  // atomic-free placement + per-pos bucket-id fill
#pragma unroll
  for (int i = 0; i < MAXIT; ++i) {
    if (aux[i] >= 0) stage[hist[aux[i] >> 16] + (aux[i] & 0xFFFF)] = rec[i];
  }
  for (int k2 = t; k2 < NB; k2 += 512) {
    const int st = hist[k2];
    const int en = (k2 == NB - 1) ? TILE : hist[k2 + 1];
    for (int p = st; p < en; ++p) bid[p] = (unsigned short)k2;
  }
  __syncthreads();

  // write-out in position order (L2-merged lines); per-bucket window clamp
  for (int pos = t; pos < TILE; pos += 512) {
    const int bb = bid[pos];
    const int idx = delta[bb] + pos;
    if (idx < (bb + 1) * RSZ) recs[idx] = stage[pos];
  }
}

// Per-bucket LDS counting sort + layer-1 aggregation + layer-2 projection.
// 1024 blocks = exactly 4/CU (LDS ~17KB, VGPR capped 64 via min-waves=8).
// Sorted list stays in LDS: no write-back, no node_off/cnt.
__global__ __launch_bounds__(512, 8) void k_sortagg1(
    const int* __restrict__ gcur, const int* __restrict__ recs,
    const unsigned short* __restrict__ p1h, const float* __restrict__ q1b,
    const float* __restrict__ Wl2, const float* __restrict__ Wr2,
    float* __restrict__ p2, float* __restrict__ r2,
    float* __restrict__ deg_inv) {
  __shared__ int hist[128];    // counts (zero-padded to 128)
  __shared__ int nstart[128];  // exclusive scan
  __shared__ int ssort[RSZ];
  __shared__ float sWl[16], sWr[16];
  const int t = threadIdx.x;
  const int kb = blockIdx.x;
  const int b0 = kb * RSZ;
  const int gend = b0 + min(gcur[kb * 16], RSZ);
  if (t < 128) hist[t] = 0;
  if (t < 16) {
    sWl[t] = Wl2[t];
    sWr[t] = Wr2[t];
  }
  __syncthreads();

  int rc[MAXB], ax[MAXB];  // ax = (local<<13) | rank
#pragma unroll
  for (int i = 0; i < MAXB; ++i) {
    const int r = b0 + t + i * 512;
    if (r < gend) {
      const int rv = recs[r];
      const int local = rv >> 17;
      const int rank = atomicAdd(&hist[local], 1);
      rc[i] = rv & 0x1FFFF;
      ax[i] = (local << 13) | rank;
    } else {
      ax[i] = -1;
    }
  }
  __syncthreads();

  // exclusive scan of hist[128] -> nstart
  {
    const int v = (t < 128) ? hist[t] : 0;
    if (t < 128) nstart[t] = v;
    __syncthreads();
#pragma unroll
    for (int o = 1; o < 128; o <<= 1) {
      const int a = (t < 128 && t >= o) ? nstart[t - o] : 0;
      __syncthreads();
      if (t < 128) nstart[t] += a;
      __syncthreads();
    }
    if (t < 128) nstart[t] -= v;
  }
  __syncthreads();

  // atomic-free placement into LDS
#pragma unroll
  for (int i = 0; i < MAXB; ++i) {
    if (ax[i] >= 0) ssort[nstart[ax[i] >> 13] + (ax[i] & 0x1FFF)] = rc[i];
  }
  __syncthreads();

  // aggregation: 4 lanes/node; quad = (edge-parity<<1)|channel-half
  const int quad = t & 3;
  const int half = quad & 1;
  const int epar = quad >> 1;
  const unsigned short* pb = p1h + half * 8;
  const int local = t >> 2;  // 0..127; BKN=98 -> lanes t>=392 idle here
  if (local < BKN) {
    const int n = kb * BKN + local;
    if (n < N_NODES) {
      const int st = nstart[local];
      const int k = hist[local];

      float acc[8];
#pragma unroll
      for (int i = 0; i < 8; ++i) acc[i] = 0.f;
      int j = epar;
      for (; j + 6 < k; j += 8) {
        const int s0 = ssort[st + j], s1 = ssort[st + j + 2],
                  s2 = ssort[st + j + 4], s3 = ssort[st + j + 6];
        const uint4 w0 = *(const uint4*)(pb + (size_t)s0 * 16);
        const uint4 w1 = *(const uint4*)(pb + (size_t)s1 * 16);
        const uint4 w2 = *(const uint4*)(pb + (size_t)s2 * 16);
        const uint4 w3 = *(const uint4*)(pb + (size_t)s3 * 16);
        acc[0] +=
            (bf2f_lo(w0.x) + bf2f_lo(w1.x)) + (bf2f_lo(w2.x) + bf2f_lo(w3.x));
        acc[1] +=
            (bf2f_hi(w0.x) + bf2f_hi(w1.x)) + (bf2f_hi(w2.x) + bf2f_hi(w3.x));
        acc[2] +=
            (bf2f_lo(w0.y) + bf2f_lo(w1.y)) + (bf2f_lo(w2.y) + bf2f_lo(w3.y));
        acc[3] +=
            (bf2f_hi(w0.y) + bf2f_hi(w1.y)) + (bf2f_hi(w2.y) + bf2f_hi(w3.y));
        acc[4] +=
            (bf2f_lo(w0.z) + bf2f_lo(w1.z)) + (bf2f_lo(w2.z) + bf2f_lo(w3.z));
        acc[5] +=
            (bf2f_hi(w0.z) + bf2f_hi(w1.z)) + (bf2f_hi(w2.z) + bf2f_hi(w3.z));
        acc[6] +=
            (bf2f_lo(w0.w) + bf2f_lo(w1.w)) + (bf2f_lo(w2.w) + bf2f_lo(w3.w));
        acc[7] +=
            (bf2f_hi(w0.w) + bf2f_hi(w1.w)) + (bf2f_hi(w2.w) + bf2f_hi(w3.w));
      }
      for (; j < k; j += 2) {
        const uint4 w = *(const uint4*)(pb + (size_t)ssort[st + j] * 16);
        acc[0] += bf2f_lo(w.x);
        acc[1] += bf2f_hi(w.x);
        acc[2] += bf2f_lo(w.y);
        acc[3] += bf2f_hi(w.y);
        acc[4] += bf2f_lo(w.z);
        acc[5] += bf2f_hi(w.z);
        acc[6] += bf2f_lo(w.w);
        acc[7] += bf2f_hi(w.w);
      }
#pragma unroll
      for (int i = 0; i < 8; ++i) acc[i] += __shfl_xor(acc[i], 2);

      const float di = 1.f / fmaxf((float)k, 1.f);
      const float4* qp = (const float4*)(q1b + (size_t)n * 16 + half * 8);
      const float4 qa = qp[0], qb = qp[1];
      float h[8];
      h[0] = fmaxf(fmaf(acc[0], di, qa.x), 0.f);
      h[1] = fmaxf(fmaf(acc[1], di, qa.y), 0.f);
      h[2] = fmaxf(fmaf(acc[2], di, qa.z), 0.f);
      h[3] = fmaxf(fmaf(acc[3], di, qa.w), 0.f);
      h[4] = fmaxf(fmaf(acc[4], di, qb.x), 0.f);
      h[5] = fmaxf(fmaf(acc[5], di, qb.y), 0.f);
      h[6] = fmaxf(fmaf(acc[6], di, qb.z), 0.f);
      h[7] = fmaxf(fmaf(acc[7], di, qb.w), 0.f);
      float pa = 0.f, pbv = 0.f;
#pragma unroll
      for (int i = 0; i < 8; ++i) {
        pa = fmaf(h[i], sWl[half * 8 + i], pa);
        pbv = fmaf(h[i], sWr[half * 8 + i], pbv);
      }
      pa += __shfl_xor(pa, 1);
      pbv += __shfl_xor(pbv, 1);
      if (quad == 0) {
        p2[n] = pa;
        r2[n] = pbv;
        deg_inv[n] = di;
      }
    }
  }
}

// layer-2 aggregation from pass-A-ordered recs (no sorted list needed):
// linear recs read + random p2 gather + 1 LDS f32 atomicAdd per edge.
// 1024 blocks = exactly 4/CU.
__global__ __launch_bounds__(512, 8) void k_agg2out(
    const int* __restrict__ gcur, const int* __restrict__ recs,
    const float* __restrict__ p2, const float* __restrict__ r2,
    const float* __restrict__ deg_inv, const float* __restrict__ b2,
    float* __restrict__ out) {
  __shared__ float acc[BKN];
  const int t = threadIdx.x;
  const int kb = blockIdx.x;
  if (t < BKN) acc[t] = 0.f;
  __syncthreads();

  const int b0 = kb * RSZ;
  const int cnt = min(gcur[kb * 16], RSZ);
  int r = t;
  // 4-wide batch: independent gathers in flight before the LDS atomics
  for (; r + 1536 < cnt; r += 2048) {
    const int rv0 = recs[b0 + r];
    const int rv1 = recs[b0 + r + 512];
    const int rv2 = recs[b0 + r + 1024];
    const int rv3 = recs[b0 + r + 1536];
    const float v0 = p2[rv0 & 0x1FFFF];
    const float v1 = p2[rv1 & 0x1FFFF];
    const float v2 = p2[rv2 & 0x1FFFF];
    const float v3 = p2[rv3 & 0x1FFFF];
    atomicAdd(&acc[rv0 >> 17], v0);
    atomicAdd(&acc[rv1 >> 17], v1);
    atomicAdd(&acc[rv2 >> 17], v2);
    atomicAdd(&acc[rv3 >> 17], v3);
  }
  for (; r < cnt; r += 512) {
    const int rv = recs[b0 + r];
    atomicAdd(&acc[rv >> 17], p2[rv & 0x1FFFF]);
  }
  __syncthreads();

  if (t < BKN) {
    const int n = kb * BKN + t;
    if (n < N_NODES) out[n] = fmaf(acc[t], deg_inv[n], r2[n] + b2[0]);
  }
}

extern "C" void kernel_launch(void* const* d_in, const int* in_sizes, int n_in,
                              void* d_out, int out_size, void* d_ws,
                              size_t ws_size, hipStream_t stream) {
  const float* x   = (const float*)d_in[0];
  const int*   ei  = (const int*)d_in[1];
  const float* Wl1 = (const float*)d_in[2];
  const float* Wr1 = (const float*)d_in[3];
  const float* b1  = (const float*)d_in[4];
  const float* Wl2 = (const float*)d_in[5];
  const float* Wr2 = (const float*)d_in[6];
  const float* b2  = (const float*)d_in[7];
  float* out = (float*)d_out;

  const size_t N = N_NODES;
  int* wi = (int*)d_ws;
  int* gcur = wi;                                    // NB*16 = 16384 ints
  int* recs = wi + NB * 16;                          // NB*RSZ ints
  unsigned short* p1h = (unsigned short*)(recs + (size_t)NB * RSZ);
  float* q1b     = (float*)(p1h + 16 * N);           // 16N floats
  float* p2      = q1b + 16 * N;
  float* r2      = p2 + N;
  float* deg_inv = r2 + N;

  k_proj1<<<(N_NODES + 255) / 256, 256, 0, stream>>>(x, Wl1, Wr1, b1, p1h,
                                                     q1b, gcur);
  k_bscatter<<<NTILES, 512, 0, stream>>>(ei, gcur, recs);
  k_sortagg1<<<NB, 512, 0, stream>>>(gcur, recs, p1h, q1b, Wl2, Wr2, p2, r2,
                                     deg_inv);
  k_agg2out<<<NB, 512, 0, stream>>>(gcur, recs, p2, r2, deg_inv, b2, out);
}